// Round 18
// baseline (143.849 us; speedup 1.0000x reference)
//
#include <hip/hip_runtime.h>

#define NB 8
#define NV 12288
#define NE 147456
#define CFM 384
#define CU 61
#define FEPS 0.005f

typedef unsigned short ushort_t;
typedef unsigned int uint_t;
typedef __attribute__((ext_vector_type(8))) unsigned short ushort8v;

__device__ inline float b2f(ushort_t u) {
    return __uint_as_float(((uint_t)u) << 16);
}
__device__ inline ushort_t f2b(float f) {   // round-nearest-even
    uint_t u = __float_as_uint(f);
    return (ushort_t)((u + 0x7fffu + ((u >> 16) & 1u)) >> 16);
}

// ---- L1: k_wt (blocks 0..47) || k_count (blocks 48..335), 512 thr ----
__global__ __launch_bounds__(512) void kL1(const float* __restrict__ cw,
                                           float* __restrict__ cwT,
                                           const int* __restrict__ erow,
                                           int* __restrict__ counts) {
    if (blockIdx.x < 48) {               // transpose conv_w -> cwT[384][64]
        int idx = blockIdx.x * 512 + threadIdx.x;   // 24576
        int c = idx >> 6, o = idx & 63;
        cwT[idx] = (o < CU) ? cw[o * CFM + c] : 0.f;
    } else {                             // degree count
        int e = (blockIdx.x - 48) * 512 + threadIdx.x;
        if (e < NE) atomicAdd(&counts[erow[e]], 1);
    }
}

// conv body: pf[b][p][o] = sum_c cwT[c][o]*fm[b][c][p], bf16 out.
// 512 thr = 64 pos x 8 og-waves of 8 outputs (s_load weights); T14 prefetch +
// double-buffered LDS -> one barrier per chunk.
__device__ void conv_body(int bid, float* smem, const float* __restrict__ fm,
                          const float* __restrict__ cwT, ushort_t* __restrict__ pf) {
    int tid = threadIdx.x;
    int lane = tid & 63;
    int og = __builtin_amdgcn_readfirstlane(tid >> 6);   // 0..7, wave-uniform
    int idx0 = bid * 64;
    int b = idx0 >> 12, p0 = idx0 & 4095;
    const float* fb = fm + (size_t)b * CFM * 4096 + p0;
    int sc = tid >> 4, spq = tid & 15;
    const float* saddr = fb + (size_t)sc * 4096 + spq * 4;

    float acc[8];
#pragma unroll
    for (int o = 0; o < 8; o++) acc[o] = 0.f;

    float4 nxt = *(const float4*)saddr;                  // preload chunk 0
    int buf = 0;
    for (int cc = 0; cc < CFM; cc += 32) {
        float* ftb = smem + buf * 2048;                  // [32][64]
        *(float4*)(ftb + sc * 64 + spq * 4) = nxt;       // vmcnt waits here only
        __syncthreads();                                 // tile ready (single barrier)
        if (cc + 32 < CFM)
            nxt = *(const float4*)(saddr + (size_t)(cc + 32) * 4096);
#pragma unroll 8
        for (int c = 0; c < 32; c++) {
            float fv = ftb[c * 64 + lane];
            const float4* w4 = (const float4*)(cwT + (cc + c) * 64 + og * 8);
            float4 wa = w4[0], wb = w4[1];
            float w[8] = {wa.x, wa.y, wa.z, wa.w, wb.x, wb.y, wb.z, wb.w};
#pragma unroll
            for (int o = 0; o < 8; o++) acc[o] = fmaf(fv, w[o], acc[o]);
        }
        buf ^= 1;                                        // next write -> other buffer
    }
    uint_t pk[4];
#pragma unroll
    for (int j = 0; j < 4; j++)
        pk[j] = (uint_t)f2b(acc[2 * j]) | ((uint_t)f2b(acc[2 * j + 1]) << 16);
    uint4* outp = (uint4*)(pf + (size_t)(idx0 + lane) * 64 + og * 8);
    outp[0] = make_uint4(pk[0], pk[1], pk[2], pk[3]);
}

// scan body: exclusive prefix over 12288 counts; 512 thr x 24 bins
__device__ void scan_body(int* ipart, const int* __restrict__ counts,
                          int* __restrict__ offs) {
    int t = threadIdx.x;
    int base = t * 24;
    int local[24];
    int s = 0;
#pragma unroll
    for (int i = 0; i < 24; i++) { local[i] = s; s += counts[base + i]; }
    ipart[t] = s;
    __syncthreads();
    for (int off = 1; off < 512; off <<= 1) {
        int v = (t >= off) ? ipart[t - off] : 0;
        __syncthreads();
        ipart[t] += v;
        __syncthreads();
    }
    int prefix = ipart[t] - s;   // exclusive
#pragma unroll
    for (int i = 0; i < 24; i++) offs[base + i] = prefix + local[i];
}

// ---- L2: k_scan (block 0) || k_conv (blocks 1..512), 512 thr, 16 KB LDS ----
__global__ __launch_bounds__(512) void kL2(const float* __restrict__ fm,
                                           const float* __restrict__ cwT,
                                           ushort_t* __restrict__ pf,
                                           const int* __restrict__ counts,
                                           int* __restrict__ offs) {
    __shared__ float smem[2 * 32 * 64];   // 16 KB (conv dbuf; scan uses 2 KB)
    if (blockIdx.x == 0) {
        scan_body((int*)smem, counts, offs);
    } else {
        conv_body(blockIdx.x - 1, smem, fm, cwT, pf);
    }
}

// sample body: projection + depth visibility + feature bilinear -> xfeat bf16
__device__ void sample_body(int t, const float* __restrict__ depth,
                            const ushort_t* __restrict__ pf,
                            const float* __restrict__ verts,
                            const float* __restrict__ fz,
                            const float* __restrict__ cz,
                            const float* __restrict__ convb,
                            ushort_t* __restrict__ xfeat) {
    int gid = t >> 4;                 // b*NV+v
    int ln = t & 15;
    int b = gid / NV;
    int v = gid - b * NV;
    const float* vp = verts + (size_t)gid * 3;
    float vx = vp[0], vy = vp[1], vz = vp[2];
    float fzb = fz[b], czb = cz[2 * b];
    float gx = fzb * vx + czb;
    float gy = fzb * vy + czb;
    float gz = fzb * (vz + 100.f);

    float px = (gx + 1.f) * 64.f - 0.5f;
    float py = (gy + 1.f) * 64.f - 0.5f;
    float fx0 = floorf(px), fy0 = floorf(py);
    float wx1 = px - fx0, wy1 = py - fy0, wx0 = 1.f - wx1, wy0 = 1.f - wy1;
    int x0 = (int)fx0, y0 = (int)fy0;
    const float* dmb = depth + (size_t)b * 128 * 128;
    float d00 = 0.f, d01 = 0.f, d10 = 0.f, d11 = 0.f;
    bool X0 = (x0 >= 0 && x0 < 128), X1 = (x0 + 1 >= 0 && x0 + 1 < 128);
    bool Y0 = (y0 >= 0 && y0 < 128), Y1 = (y0 + 1 >= 0 && y0 + 1 < 128);
    int xa = min(max(x0, 0), 127), xb = min(max(x0 + 1, 0), 127);
    int ya = min(max(y0, 0), 127), yb = min(max(y0 + 1, 0), 127);
    if (Y0 && X0) d00 = dmb[ya * 128 + xa];
    if (Y0 && X1) d01 = dmb[ya * 128 + xb];
    if (Y1 && X0) d10 = dmb[yb * 128 + xa];
    if (Y1 && X1) d11 = dmb[yb * 128 + xb];
    float sd = d00 * wy0 * wx0 + d01 * wy0 * wx1 + d10 * wy1 * wx0 + d11 * wy1 * wx1;
    float vis = (fabsf(sd - gz) < FEPS) ? 1.f : 0.f;

    float qx = (gx + 1.f) * 32.f - 0.5f;
    float qy = (gy + 1.f) * 32.f - 0.5f;
    float gx0 = floorf(qx), gy0 = floorf(qy);
    float ax1 = qx - gx0, ay1 = qy - gy0, ax0 = 1.f - ax1, ay0 = 1.f - ay1;
    int icx0 = (int)gx0, icy0 = (int)gy0;
    bool FX0 = (icx0 >= 0 && icx0 < 64), FX1 = (icx0 + 1 >= 0 && icx0 + 1 < 64);
    bool FY0 = (icy0 >= 0 && icy0 < 64), FY1 = (icy0 + 1 >= 0 && icy0 + 1 < 64);
    int fxa = min(max(icx0, 0), 63), fxb = min(max(icx0 + 1, 0), 63);
    int fya = min(max(icy0, 0), 63), fyb = min(max(icy0 + 1, 0), 63);
    float m00 = (FY0 && FX0) ? ay0 * ax0 : 0.f;
    float m01 = (FY0 && FX1) ? ay0 * ax1 : 0.f;
    float m10 = (FY1 && FX0) ? ay1 * ax0 : 0.f;
    float m11 = (FY1 && FX1) ? ay1 * ax1 : 0.f;
    const ushort_t* pfb = pf + (size_t)b * 4096 * 64;
    const ushort_t* p00 = pfb + ((size_t)fya * 64 + fxa) * 64;
    const ushort_t* p01 = pfb + ((size_t)fya * 64 + fxb) * 64;
    const ushort_t* p10 = pfb + ((size_t)fyb * 64 + fxa) * 64;
    const ushort_t* p11 = pfb + ((size_t)fyb * 64 + fxb) * 64;

    ushort_t* xr = xfeat + ((size_t)v * NB + b) * 64;
#pragma unroll
    for (int j = 0; j < 4; j++) {
        int c = ln + 16 * j;
        if (c < CU) {
            float val = m00 * b2f(p00[c]) + m01 * b2f(p01[c])
                      + m10 * b2f(p10[c]) + m11 * b2f(p11[c]);
            xr[c] = f2b(vis * val + convb[c]);
        } else {
            xr[c] = f2b(vp[c - CU]);
        }
    }
}

// ---- L3: k_fill (blocks 0..287) || k_sample (blocks 288..3359), 512 thr ----
__global__ __launch_bounds__(512) void kL3(const int* __restrict__ erow,
                                           const int* __restrict__ ecol,
                                           const int* __restrict__ offs,
                                           int* __restrict__ cursor,
                                           int* __restrict__ csr,
                                           const float* __restrict__ depth,
                                           const ushort_t* __restrict__ pf,
                                           const float* __restrict__ verts,
                                           const float* __restrict__ fz,
                                           const float* __restrict__ cz,
                                           const float* __restrict__ convb,
                                           ushort_t* __restrict__ xfeat) {
    if (blockIdx.x < 288) {
        int e = blockIdx.x * 512 + threadIdx.x;
        if (e < NE) {
            int r = erow[e];
            int pos = offs[r] + atomicAdd(&cursor[r], 1);
            csr[pos] = ecol[e];
        }
    } else {
        int t = (blockIdx.x - 288) * 512 + threadIdx.x;
        sample_body(t, depth, pf, verts, fz, cz, convb, xfeat);
    }
}

// FUSED gather + MLP: block = 256 = 8 vertices (64 rows) x 4 waves.
// Phase 0 QUARTER-WAVE gather: each quarter (16 lanes) handles a different
// edge concurrently -> 4 independent load chains/wave, serial depth n/4;
// lane covers 32 elems (64 B) of the 512-elem row; cross-quarter combine
// via shfl_xor butterfly. Phases 1/2 unchanged (proven GEMM + 2-phase reduce).
__global__ __launch_bounds__(256) void k_gmlp(
        const int* __restrict__ counts, const int* __restrict__ offs,
        const int* __restrict__ csr, const ushort_t* __restrict__ xfeat,
        const float* __restrict__ W1, const float* __restrict__ b1,
        const float* __restrict__ W2, const float* __restrict__ Wdv,
        const float* __restrict__ verts, ushort_t* __restrict__ y2,
        float* __restrict__ out) {
    __shared__ float smem[2 * 64 * 37];   // 18944 B
    float* xl = smem;                     // [64][65], phases 0-1
    float* part2 = smem;                  // [2][64][37], phase 2
    int tid = threadIdx.x;
    int lane = tid & 63;
    int w = __builtin_amdgcn_readfirstlane(tid >> 6);   // 0..3, wave-uniform
    int vbase = blockIdx.x * 8;          // 1536 blocks x 8 vertices

    // ---- phase 0: quarter-wave gather, 2 vertices per wave
    int q = lane >> 4, s = lane & 15;    // quarter, sublane
#pragma unroll
    for (int vs = 0; vs < 2; vs++) {
        int vloc = 2 * w + vs;
        int vid = vbase + vloc;          // wave-uniform
        int beg = offs[vid], n = counts[vid];
        float a[32];
#pragma unroll
        for (int t = 0; t < 32; t++) a[t] = 0.f;
        for (int j = q; j < n; j += 4) { // quarter q owns edges j = q, q+4, ...
            int c = csr[beg + j];        // per-quarter index (broadcast in quarter)
            const ushort8v* src = (const ushort8v*)(xfeat + (size_t)c * 512 + s * 32);
            ushort8v u0 = src[0], u1 = src[1], u2 = src[2], u3 = src[3];
#pragma unroll
            for (int t = 0; t < 8; t++) {
                a[t]      += b2f(u0[t]);
                a[8 + t]  += b2f(u1[t]);
                a[16 + t] += b2f(u2[t]);
                a[24 + t] += b2f(u3[t]);
            }
        }
        // combine quarters: butterfly over lane bits 4,5
#pragma unroll
        for (int t = 0; t < 32; t++) {
            a[t] += __shfl_xor(a[t], 16, 64);
            a[t] += __shfl_xor(a[t], 32, 64);
        }
        if (q == 0) {
            float dinv = 1.f / fmaxf((float)n, 1.f);
            // lane s covers elems s*32..+31: row = vloc*8 + (s>>1), ch0 = (s&1)*32
            float* dst = xl + ((size_t)(vloc * 8 + (s >> 1))) * 65 + (s & 1) * 32;
#pragma unroll
            for (int t = 0; t < 32; t++) dst[t] = a[t] * dinv;
        }
    }
    __syncthreads();

    // ---- phase 1: GEMM1  h = relu(x @ W1 + b1)
    float h[32];
    {
        const float* bp = b1 + w * 32;
#pragma unroll
        for (int j = 0; j < 32; j++) h[j] = bp[j];
    }
    const float* xrow = xl + lane * 65;
#pragma unroll 8
    for (int k = 0; k < 64; k++) {
        float xv = xrow[k];
        const float* wk = W1 + k * 128 + w * 32;   // uniform -> s_load
#pragma unroll
        for (int j = 0; j < 32; j++) h[j] = fmaf(xv, wk[j], h[j]);
    }
#pragma unroll
    for (int j = 0; j < 32; j++) h[j] = fmaxf(h[j], 0.f);

    // GEMM2 partial: this wave's 32 hidden rows of W2/Wdv
    float acc2[35];
#pragma unroll
    for (int j = 0; j < 35; j++) acc2[j] = 0.f;
    const float* w2p = W2 + (size_t)(w * 32) * 32;
    const float* wdp = Wdv + (size_t)(w * 32) * 3;
#pragma unroll 4
    for (int kc = 0; kc < 32; kc++) {
        float hv = h[kc];
#pragma unroll
        for (int j = 0; j < 32; j++)
            acc2[j] = fmaf(hv, w2p[kc * 32 + j], acc2[j]);
        acc2[32] = fmaf(hv, wdp[kc * 3 + 0], acc2[32]);
        acc2[33] = fmaf(hv, wdp[kc * 3 + 1], acc2[33]);
        acc2[34] = fmaf(hv, wdp[kc * 3 + 2], acc2[34]);
    }
    __syncthreads();   // xl reads done -> smem becomes part2

    // ---- phase 2: 2-phase cross-wave reduction
    if (w >= 2) {
        float* pp = part2 + ((size_t)(w - 2) * 64 + lane) * 37;
#pragma unroll
        for (int j = 0; j < 35; j++) pp[j] = acc2[j];
    }
    __syncthreads();
    if (w < 2) {
        const float* pp = part2 + ((size_t)w * 64 + lane) * 37;
#pragma unroll
        for (int j = 0; j < 35; j++) acc2[j] += pp[j];
    }
    __syncthreads();   // WAR before wave 1 overwrites
    if (w == 1) {
        float* pp = part2 + (size_t)lane * 37;
#pragma unroll
        for (int j = 0; j < 35; j++) pp[j] = acc2[j];
    }
    __syncthreads();
    if (w == 0) {
        const float* pp = part2 + (size_t)lane * 37;
#pragma unroll
        for (int j = 0; j < 35; j++) acc2[j] += pp[j];
        int row = vbase * 8 + lane;     // = v*8+b, vertex-major
        uint_t pk[16];
#pragma unroll
        for (int j = 0; j < 16; j++)
            pk[j] = (uint_t)f2b(acc2[2 * j]) | ((uint_t)f2b(acc2[2 * j + 1]) << 16);
        uint4* yp = (uint4*)(y2 + (size_t)row * 32);
#pragma unroll
        for (int j = 0; j < 4; j++)
            yp[j] = make_uint4(pk[4 * j], pk[4 * j + 1], pk[4 * j + 2], pk[4 * j + 3]);
        float e0 = acc2[32], e1 = acc2[33], e2 = acc2[34];
        int v = row >> 3, b = row & 7;
        const float* vp = verts + ((size_t)b * NV + v) * 3;
        float* orow = out + ((size_t)b * NV + v) * 38;
        orow[32] = (vp[0] + e0) * 1000.f;
        orow[33] = (vp[1] + e1) * 1000.f;
        orow[34] = (vp[2] + e2) * 1000.f;
        orow[35] = e0 * 1000.f;
        orow[36] = e1 * 1000.f;
        orow[37] = e2 * 1000.f;
    }
}

// gather-agg over y2: quarter-wave per edge (4 chains), lane covers 16 elems
// (32 B) of the 256-elem row; shfl_xor combine; quarter 0 writes out[0..31].
__global__ void k_agg2(const int* __restrict__ counts, const int* __restrict__ offs,
                       const int* __restrict__ csr, const ushort_t* __restrict__ y2,
                       float* __restrict__ out) {
    int wid = (blockIdx.x * 256 + threadIdx.x) >> 6;   // vertex
    int l = threadIdx.x & 63;
    if (wid >= NV) return;
    int q = l >> 4, s = l & 15;
    int beg = offs[wid], n = counts[wid];
    float a[16];
#pragma unroll
    for (int t = 0; t < 16; t++) a[t] = 0.f;
    for (int j = q; j < n; j += 4) {
        int c = csr[beg + j];
        const ushort8v* src = (const ushort8v*)(y2 + (size_t)c * 256 + s * 16);
        ushort8v u0 = src[0], u1 = src[1];
#pragma unroll
        for (int t = 0; t < 8; t++) {
            a[t]     += b2f(u0[t]);
            a[8 + t] += b2f(u1[t]);
        }
    }
#pragma unroll
    for (int t = 0; t < 16; t++) {
        a[t] += __shfl_xor(a[t], 16, 64);
        a[t] += __shfl_xor(a[t], 32, 64);
    }
    if (q == 0) {
        float dinv = 1.f / fmaxf((float)n, 1.f);
        // lane s covers elems s*16..+15: batch = s>>1, ch0 = (s&1)*16
        int b = s >> 1, ch0 = (s & 1) * 16;
        float* orow = out + ((size_t)b * NV + wid) * 38 + ch0;
#pragma unroll
        for (int t = 0; t < 16; t++) orow[t] = a[t] * dinv;
    }
}

extern "C" void kernel_launch(void* const* d_in, const int* in_sizes, int n_in,
                              void* d_out, int out_size, void* d_ws, size_t ws_size,
                              hipStream_t stream) {
    const float* fm  = (const float*)d_in[0];
    const float* dm  = (const float*)d_in[1];
    const float* vt  = (const float*)d_in[2];
    const float* fz  = (const float*)d_in[3];
    const float* cz  = (const float*)d_in[4];
    const float* cw  = (const float*)d_in[5];
    const float* cb  = (const float*)d_in[6];
    const float* W1  = (const float*)d_in[7];
    const float* b1  = (const float*)d_in[8];
    const float* W2  = (const float*)d_in[9];
    const float* Wdv = (const float*)d_in[10];
    const int* erow  = (const int*)d_in[11];
    const int* ecol  = (const int*)d_in[12];
    float* out = (float*)d_out;

    float* ws    = (float*)d_ws;
    float* cwT   = ws;                            // 24576 f
    ushort_t* pf = (ushort_t*)(cwT + 24576);      // 2097152 bf16 (1048576 f)
    ushort_t* xfeat = (ushort_t*)((float*)pf + 1048576);   // 6291456 bf16
    ushort_t* y2 = (ushort_t*)((float*)xfeat + 3145728);   // 3145728 bf16
    int* counts  = (int*)((float*)y2 + 1572864);  // 12288
    int* offs    = counts + 12288;
    int* cursor  = offs + 12288;
    int* csr     = cursor + 12288;                // 147456

    hipMemsetAsync(counts, 0, 12288 * sizeof(int), stream);
    hipMemsetAsync(cursor, 0, 12288 * sizeof(int), stream);

    kL1<<<336, 512, 0, stream>>>(cw, cwT, erow, counts);
    kL2<<<513, 512, 0, stream>>>(fm, cwT, pf, counts, offs);
    kL3<<<3360, 512, 0, stream>>>(erow, ecol, offs, cursor, csr,
                                  dm, pf, vt, fz, cz, cb, xfeat);
    k_gmlp<<<1536, 256, 0, stream>>>(counts, offs, csr, xfeat,
                                     W1, b1, W2, Wdv, vt, y2, out);
    k_agg2<<<3072, 256, 0, stream>>>(counts, offs, csr, y2, out);
}

// Round 19
// 134.287 us; speedup vs baseline: 1.0712x; 1.0712x over previous
//
#include <hip/hip_runtime.h>

#define NB 8
#define NV 12288
#define NE 147456
#define CFM 384
#define CU 61
#define FEPS 0.005f

typedef unsigned short ushort_t;
typedef unsigned int uint_t;
typedef __attribute__((ext_vector_type(8))) unsigned short ushort8v;

__device__ inline float b2f(ushort_t u) {
    return __uint_as_float(((uint_t)u) << 16);
}
__device__ inline ushort_t f2b(float f) {   // round-nearest-even
    uint_t u = __float_as_uint(f);
    return (ushort_t)((u + 0x7fffu + ((u >> 16) & 1u)) >> 16);
}

// ---- L1: k_wt (blocks 0..47) || k_count (blocks 48..335), 512 thr ----
__global__ __launch_bounds__(512) void kL1(const float* __restrict__ cw,
                                           float* __restrict__ cwT,
                                           const int* __restrict__ erow,
                                           int* __restrict__ counts) {
    if (blockIdx.x < 48) {               // transpose conv_w -> cwT[384][64]
        int idx = blockIdx.x * 512 + threadIdx.x;   // 24576
        int c = idx >> 6, o = idx & 63;
        cwT[idx] = (o < CU) ? cw[o * CFM + c] : 0.f;
    } else {                             // degree count
        int e = (blockIdx.x - 48) * 512 + threadIdx.x;
        if (e < NE) atomicAdd(&counts[erow[e]], 1);
    }
}

// conv body: pf[b][p][o] = sum_c cwT[c][o]*fm[b][c][p], bf16 out.
// 512 thr = 64 pos x 8 og-waves of 8 outputs (s_load weights); T14 prefetch +
// double-buffered LDS -> one barrier per chunk.
__device__ void conv_body(int bid, float* smem, const float* __restrict__ fm,
                          const float* __restrict__ cwT, ushort_t* __restrict__ pf) {
    int tid = threadIdx.x;
    int lane = tid & 63;
    int og = __builtin_amdgcn_readfirstlane(tid >> 6);   // 0..7, wave-uniform
    int idx0 = bid * 64;
    int b = idx0 >> 12, p0 = idx0 & 4095;
    const float* fb = fm + (size_t)b * CFM * 4096 + p0;
    int sc = tid >> 4, spq = tid & 15;
    const float* saddr = fb + (size_t)sc * 4096 + spq * 4;

    float acc[8];
#pragma unroll
    for (int o = 0; o < 8; o++) acc[o] = 0.f;

    float4 nxt = *(const float4*)saddr;                  // preload chunk 0
    int buf = 0;
    for (int cc = 0; cc < CFM; cc += 32) {
        float* ftb = smem + buf * 2048;                  // [32][64]
        *(float4*)(ftb + sc * 64 + spq * 4) = nxt;       // vmcnt waits here only
        __syncthreads();                                 // tile ready (single barrier)
        if (cc + 32 < CFM)
            nxt = *(const float4*)(saddr + (size_t)(cc + 32) * 4096);
#pragma unroll 8
        for (int c = 0; c < 32; c++) {
            float fv = ftb[c * 64 + lane];
            const float4* w4 = (const float4*)(cwT + (cc + c) * 64 + og * 8);
            float4 wa = w4[0], wb = w4[1];
            float w[8] = {wa.x, wa.y, wa.z, wa.w, wb.x, wb.y, wb.z, wb.w};
#pragma unroll
            for (int o = 0; o < 8; o++) acc[o] = fmaf(fv, w[o], acc[o]);
        }
        buf ^= 1;                                        // next write -> other buffer
    }
    uint_t pk[4];
#pragma unroll
    for (int j = 0; j < 4; j++)
        pk[j] = (uint_t)f2b(acc[2 * j]) | ((uint_t)f2b(acc[2 * j + 1]) << 16);
    uint4* outp = (uint4*)(pf + (size_t)(idx0 + lane) * 64 + og * 8);
    outp[0] = make_uint4(pk[0], pk[1], pk[2], pk[3]);
}

// scan body: exclusive prefix over 12288 counts; 512 thr x 24 bins
__device__ void scan_body(int* ipart, const int* __restrict__ counts,
                          int* __restrict__ offs) {
    int t = threadIdx.x;
    int base = t * 24;
    int local[24];
    int s = 0;
#pragma unroll
    for (int i = 0; i < 24; i++) { local[i] = s; s += counts[base + i]; }
    ipart[t] = s;
    __syncthreads();
    for (int off = 1; off < 512; off <<= 1) {
        int v = (t >= off) ? ipart[t - off] : 0;
        __syncthreads();
        ipart[t] += v;
        __syncthreads();
    }
    int prefix = ipart[t] - s;   // exclusive
#pragma unroll
    for (int i = 0; i < 24; i++) offs[base + i] = prefix + local[i];
}

// ---- L2: k_scan (block 0) || k_conv (blocks 1..512), 512 thr, 16 KB LDS ----
__global__ __launch_bounds__(512) void kL2(const float* __restrict__ fm,
                                           const float* __restrict__ cwT,
                                           ushort_t* __restrict__ pf,
                                           const int* __restrict__ counts,
                                           int* __restrict__ offs) {
    __shared__ float smem[2 * 32 * 64];   // 16 KB (conv dbuf; scan uses 2 KB)
    if (blockIdx.x == 0) {
        scan_body((int*)smem, counts, offs);
    } else {
        conv_body(blockIdx.x - 1, smem, fm, cwT, pf);
    }
}

// sample body: projection + depth visibility + feature bilinear -> xfeat bf16
__device__ void sample_body(int t, const float* __restrict__ depth,
                            const ushort_t* __restrict__ pf,
                            const float* __restrict__ verts,
                            const float* __restrict__ fz,
                            const float* __restrict__ cz,
                            const float* __restrict__ convb,
                            ushort_t* __restrict__ xfeat) {
    int gid = t >> 4;                 // b*NV+v
    int ln = t & 15;
    int b = gid / NV;
    int v = gid - b * NV;
    const float* vp = verts + (size_t)gid * 3;
    float vx = vp[0], vy = vp[1], vz = vp[2];
    float fzb = fz[b], czb = cz[2 * b];
    float gx = fzb * vx + czb;
    float gy = fzb * vy + czb;
    float gz = fzb * (vz + 100.f);

    float px = (gx + 1.f) * 64.f - 0.5f;
    float py = (gy + 1.f) * 64.f - 0.5f;
    float fx0 = floorf(px), fy0 = floorf(py);
    float wx1 = px - fx0, wy1 = py - fy0, wx0 = 1.f - wx1, wy0 = 1.f - wy1;
    int x0 = (int)fx0, y0 = (int)fy0;
    const float* dmb = depth + (size_t)b * 128 * 128;
    float d00 = 0.f, d01 = 0.f, d10 = 0.f, d11 = 0.f;
    bool X0 = (x0 >= 0 && x0 < 128), X1 = (x0 + 1 >= 0 && x0 + 1 < 128);
    bool Y0 = (y0 >= 0 && y0 < 128), Y1 = (y0 + 1 >= 0 && y0 + 1 < 128);
    int xa = min(max(x0, 0), 127), xb = min(max(x0 + 1, 0), 127);
    int ya = min(max(y0, 0), 127), yb = min(max(y0 + 1, 0), 127);
    if (Y0 && X0) d00 = dmb[ya * 128 + xa];
    if (Y0 && X1) d01 = dmb[ya * 128 + xb];
    if (Y1 && X0) d10 = dmb[yb * 128 + xa];
    if (Y1 && X1) d11 = dmb[yb * 128 + xb];
    float sd = d00 * wy0 * wx0 + d01 * wy0 * wx1 + d10 * wy1 * wx0 + d11 * wy1 * wx1;
    float vis = (fabsf(sd - gz) < FEPS) ? 1.f : 0.f;

    float qx = (gx + 1.f) * 32.f - 0.5f;
    float qy = (gy + 1.f) * 32.f - 0.5f;
    float gx0 = floorf(qx), gy0 = floorf(qy);
    float ax1 = qx - gx0, ay1 = qy - gy0, ax0 = 1.f - ax1, ay0 = 1.f - ay1;
    int icx0 = (int)gx0, icy0 = (int)gy0;
    bool FX0 = (icx0 >= 0 && icx0 < 64), FX1 = (icx0 + 1 >= 0 && icx0 + 1 < 64);
    bool FY0 = (icy0 >= 0 && icy0 < 64), FY1 = (icy0 + 1 >= 0 && icy0 + 1 < 64);
    int fxa = min(max(icx0, 0), 63), fxb = min(max(icx0 + 1, 0), 63);
    int fya = min(max(icy0, 0), 63), fyb = min(max(icy0 + 1, 0), 63);
    float m00 = (FY0 && FX0) ? ay0 * ax0 : 0.f;
    float m01 = (FY0 && FX1) ? ay0 * ax1 : 0.f;
    float m10 = (FY1 && FX0) ? ay1 * ax0 : 0.f;
    float m11 = (FY1 && FX1) ? ay1 * ax1 : 0.f;
    const ushort_t* pfb = pf + (size_t)b * 4096 * 64;
    const ushort_t* p00 = pfb + ((size_t)fya * 64 + fxa) * 64;
    const ushort_t* p01 = pfb + ((size_t)fya * 64 + fxb) * 64;
    const ushort_t* p10 = pfb + ((size_t)fyb * 64 + fxa) * 64;
    const ushort_t* p11 = pfb + ((size_t)fyb * 64 + fxb) * 64;

    ushort_t* xr = xfeat + ((size_t)v * NB + b) * 64;
#pragma unroll
    for (int j = 0; j < 4; j++) {
        int c = ln + 16 * j;
        if (c < CU) {
            float val = m00 * b2f(p00[c]) + m01 * b2f(p01[c])
                      + m10 * b2f(p10[c]) + m11 * b2f(p11[c]);
            xr[c] = f2b(vis * val + convb[c]);
        } else {
            xr[c] = f2b(vp[c - CU]);
        }
    }
}

// ---- L3: k_fill (blocks 0..287) || k_sample (blocks 288..3359), 512 thr ----
__global__ __launch_bounds__(512) void kL3(const int* __restrict__ erow,
                                           const int* __restrict__ ecol,
                                           const int* __restrict__ offs,
                                           int* __restrict__ cursor,
                                           int* __restrict__ csr,
                                           const float* __restrict__ depth,
                                           const ushort_t* __restrict__ pf,
                                           const float* __restrict__ verts,
                                           const float* __restrict__ fz,
                                           const float* __restrict__ cz,
                                           const float* __restrict__ convb,
                                           ushort_t* __restrict__ xfeat) {
    if (blockIdx.x < 288) {
        int e = blockIdx.x * 512 + threadIdx.x;
        if (e < NE) {
            int r = erow[e];
            int pos = offs[r] + atomicAdd(&cursor[r], 1);
            csr[pos] = ecol[e];
        }
    } else {
        int t = (blockIdx.x - 288) * 512 + threadIdx.x;
        sample_body(t, depth, pf, verts, fz, cz, convb, xfeat);
    }
}

// FUSED gather + MLP: block = 256 = 8 vertices (64 rows) x 4 waves.
// Phase 0: full-wave gather (16B/lane, csr wave-uniform -> s_load), 2 vertices
// per wave, MANUALLY 4-DEEP UNROLLED: 4 row loads issue back-to-back before
// any accumulate -> 4 KB in flight per chain (R15's rolled loop kept ~1).
// R18's quarter-wave variant REGRESSED (65 us: vector csr loads, 128 shfl ops,
// xl bank conflicts) — reverted. Phases 1/2 unchanged.
__global__ __launch_bounds__(256) void k_gmlp(
        const int* __restrict__ counts, const int* __restrict__ offs,
        const int* __restrict__ csr, const ushort_t* __restrict__ xfeat,
        const float* __restrict__ W1, const float* __restrict__ b1,
        const float* __restrict__ W2, const float* __restrict__ Wdv,
        const float* __restrict__ verts, ushort_t* __restrict__ y2,
        float* __restrict__ out) {
    __shared__ float smem[2 * 64 * 37];   // 18944 B
    float* xl = smem;                     // [64][65], phases 0-1
    float* part2 = smem;                  // [2][64][37], phase 2
    int tid = threadIdx.x;
    int lane = tid & 63;
    int w = __builtin_amdgcn_readfirstlane(tid >> 6);   // 0..3, wave-uniform
    int vbase = blockIdx.x * 8;          // 1536 blocks x 8 vertices

    // ---- phase 0: 4-deep unrolled gather, 2 vertices per wave
#pragma unroll
    for (int vs = 0; vs < 2; vs++) {
        int vloc = 2 * w + vs;
        int vid = vbase + vloc;          // wave-uniform
        int beg = offs[vid], n = counts[vid];
        float a[8];
#pragma unroll
        for (int t = 0; t < 8; t++) a[t] = 0.f;
        const ushort_t* xb = xfeat + lane * 8;
        int j = 0;
        for (; j + 4 <= n; j += 4) {
            int c0 = csr[beg + j], c1 = csr[beg + j + 1];
            int c2 = csr[beg + j + 2], c3 = csr[beg + j + 3];
            ushort8v u0 = *(const ushort8v*)(xb + (size_t)c0 * 512);
            ushort8v u1 = *(const ushort8v*)(xb + (size_t)c1 * 512);
            ushort8v u2 = *(const ushort8v*)(xb + (size_t)c2 * 512);
            ushort8v u3 = *(const ushort8v*)(xb + (size_t)c3 * 512);
#pragma unroll
            for (int t = 0; t < 8; t++)
                a[t] += (b2f(u0[t]) + b2f(u1[t])) + (b2f(u2[t]) + b2f(u3[t]));
        }
        for (; j < n; j++) {
            int c = csr[beg + j];
            ushort8v u = *(const ushort8v*)(xb + (size_t)c * 512);
#pragma unroll
            for (int t = 0; t < 8; t++) a[t] += b2f(u[t]);
        }
        float dinv = 1.f / fmaxf((float)n, 1.f);
        float* dst = xl + ((2 * w + vs) * 8 + (lane >> 3)) * 65 + (lane & 7) * 8;
#pragma unroll
        for (int t = 0; t < 8; t++) dst[t] = a[t] * dinv;
    }
    __syncthreads();

    // ---- phase 1: GEMM1  h = relu(x @ W1 + b1)
    float h[32];
    {
        const float* bp = b1 + w * 32;
#pragma unroll
        for (int j = 0; j < 32; j++) h[j] = bp[j];
    }
    const float* xrow = xl + lane * 65;
#pragma unroll 8
    for (int k = 0; k < 64; k++) {
        float xv = xrow[k];
        const float* wk = W1 + k * 128 + w * 32;   // uniform -> s_load
#pragma unroll
        for (int j = 0; j < 32; j++) h[j] = fmaf(xv, wk[j], h[j]);
    }
#pragma unroll
    for (int j = 0; j < 32; j++) h[j] = fmaxf(h[j], 0.f);

    // GEMM2 partial: this wave's 32 hidden rows of W2/Wdv
    float acc2[35];
#pragma unroll
    for (int j = 0; j < 35; j++) acc2[j] = 0.f;
    const float* w2p = W2 + (size_t)(w * 32) * 32;
    const float* wdp = Wdv + (size_t)(w * 32) * 3;
#pragma unroll 4
    for (int kc = 0; kc < 32; kc++) {
        float hv = h[kc];
#pragma unroll
        for (int j = 0; j < 32; j++)
            acc2[j] = fmaf(hv, w2p[kc * 32 + j], acc2[j]);
        acc2[32] = fmaf(hv, wdp[kc * 3 + 0], acc2[32]);
        acc2[33] = fmaf(hv, wdp[kc * 3 + 1], acc2[33]);
        acc2[34] = fmaf(hv, wdp[kc * 3 + 2], acc2[34]);
    }
    __syncthreads();   // xl reads done -> smem becomes part2

    // ---- phase 2: 2-phase cross-wave reduction
    if (w >= 2) {
        float* pp = part2 + ((size_t)(w - 2) * 64 + lane) * 37;
#pragma unroll
        for (int j = 0; j < 35; j++) pp[j] = acc2[j];
    }
    __syncthreads();
    if (w < 2) {
        const float* pp = part2 + ((size_t)w * 64 + lane) * 37;
#pragma unroll
        for (int j = 0; j < 35; j++) acc2[j] += pp[j];
    }
    __syncthreads();   // WAR before wave 1 overwrites
    if (w == 1) {
        float* pp = part2 + (size_t)lane * 37;
#pragma unroll
        for (int j = 0; j < 35; j++) pp[j] = acc2[j];
    }
    __syncthreads();
    if (w == 0) {
        const float* pp = part2 + (size_t)lane * 37;
#pragma unroll
        for (int j = 0; j < 35; j++) acc2[j] += pp[j];
        int row = vbase * 8 + lane;     // = v*8+b, vertex-major
        uint_t pk[16];
#pragma unroll
        for (int j = 0; j < 16; j++)
            pk[j] = (uint_t)f2b(acc2[2 * j]) | ((uint_t)f2b(acc2[2 * j + 1]) << 16);
        uint4* yp = (uint4*)(y2 + (size_t)row * 32);
#pragma unroll
        for (int j = 0; j < 4; j++)
            yp[j] = make_uint4(pk[4 * j], pk[4 * j + 1], pk[4 * j + 2], pk[4 * j + 3]);
        float e0 = acc2[32], e1 = acc2[33], e2 = acc2[34];
        int v = row >> 3, b = row & 7;
        const float* vp = verts + ((size_t)b * NV + v) * 3;
        float* orow = out + ((size_t)b * NV + v) * 38;
        orow[32] = (vp[0] + e0) * 1000.f;
        orow[33] = (vp[1] + e1) * 1000.f;
        orow[34] = (vp[2] + e2) * 1000.f;
        orow[35] = e0 * 1000.f;
        orow[36] = e1 * 1000.f;
        orow[37] = e2 * 1000.f;
    }
}

// gather-agg over y2: quarter-wave per edge (4 chains), lane covers 16 elems
// (32 B) of the 256-elem row; shfl_xor combine; quarter 0 writes out[0..31].
// (kept from R18 — the ~10 us gain there attributes to this kernel)
__global__ void k_agg2(const int* __restrict__ counts, const int* __restrict__ offs,
                       const int* __restrict__ csr, const ushort_t* __restrict__ y2,
                       float* __restrict__ out) {
    int wid = (blockIdx.x * 256 + threadIdx.x) >> 6;   // vertex
    int l = threadIdx.x & 63;
    if (wid >= NV) return;
    int q = l >> 4, s = l & 15;
    int beg = offs[wid], n = counts[wid];
    float a[16];
#pragma unroll
    for (int t = 0; t < 16; t++) a[t] = 0.f;
    for (int j = q; j < n; j += 4) {
        int c = csr[beg + j];
        const ushort8v* src = (const ushort8v*)(y2 + (size_t)c * 256 + s * 16);
        ushort8v u0 = src[0], u1 = src[1];
#pragma unroll
        for (int t = 0; t < 8; t++) {
            a[t]     += b2f(u0[t]);
            a[8 + t] += b2f(u1[t]);
        }
    }
#pragma unroll
    for (int t = 0; t < 16; t++) {
        a[t] += __shfl_xor(a[t], 16, 64);
        a[t] += __shfl_xor(a[t], 32, 64);
    }
    if (q == 0) {
        float dinv = 1.f / fmaxf((float)n, 1.f);
        int b = s >> 1, ch0 = (s & 1) * 16;
        float* orow = out + ((size_t)b * NV + wid) * 38 + ch0;
#pragma unroll
        for (int t = 0; t < 16; t++) orow[t] = a[t] * dinv;
    }
}

extern "C" void kernel_launch(void* const* d_in, const int* in_sizes, int n_in,
                              void* d_out, int out_size, void* d_ws, size_t ws_size,
                              hipStream_t stream) {
    const float* fm  = (const float*)d_in[0];
    const float* dm  = (const float*)d_in[1];
    const float* vt  = (const float*)d_in[2];
    const float* fz  = (const float*)d_in[3];
    const float* cz  = (const float*)d_in[4];
    const float* cw  = (const float*)d_in[5];
    const float* cb  = (const float*)d_in[6];
    const float* W1  = (const float*)d_in[7];
    const float* b1  = (const float*)d_in[8];
    const float* W2  = (const float*)d_in[9];
    const float* Wdv = (const float*)d_in[10];
    const int* erow  = (const int*)d_in[11];
    const int* ecol  = (const int*)d_in[12];
    float* out = (float*)d_out;

    float* ws    = (float*)d_ws;
    float* cwT   = ws;                            // 24576 f
    ushort_t* pf = (ushort_t*)(cwT + 24576);      // 2097152 bf16 (1048576 f)
    ushort_t* xfeat = (ushort_t*)((float*)pf + 1048576);   // 6291456 bf16
    ushort_t* y2 = (ushort_t*)((float*)xfeat + 3145728);   // 3145728 bf16
    int* counts  = (int*)((float*)y2 + 1572864);  // 12288
    int* offs    = counts + 12288;
    int* cursor  = offs + 12288;
    int* csr     = cursor + 12288;                // 147456

    hipMemsetAsync(counts, 0, 12288 * sizeof(int), stream);
    hipMemsetAsync(cursor, 0, 12288 * sizeof(int), stream);

    kL1<<<336, 512, 0, stream>>>(cw, cwT, erow, counts);
    kL2<<<513, 512, 0, stream>>>(fm, cwT, pf, counts, offs);
    kL3<<<3360, 512, 0, stream>>>(erow, ecol, offs, cursor, csr,
                                  dm, pf, vt, fz, cz, cb, xfeat);
    k_gmlp<<<1536, 256, 0, stream>>>(counts, offs, csr, xfeat,
                                     W1, b1, W2, Wdv, vt, y2, out);
    k_agg2<<<3072, 256, 0, stream>>>(counts, offs, csr, y2, out);
}